// Round 3
// baseline (1060.184 us; speedup 1.0000x reference)
//
#include <hip/hip_runtime.h>

using u16 = unsigned short;
using s16x8 = __attribute__((ext_vector_type(8))) short;
using f32x4 = __attribute__((ext_vector_type(4))) float;
using f32x16 = __attribute__((ext_vector_type(16))) float;

#define DEV static __device__ __forceinline__

DEV u16 bf16b(float f) {
  unsigned u = __builtin_bit_cast(unsigned, f);
  return (u16)((u + 0x7fffu + ((u >> 16) & 1u)) >> 16);
}

DEV void gload16(const void* g, void* l) {
  __builtin_amdgcn_global_load_lds((const __attribute__((address_space(1))) unsigned int*)g,
                                   (__attribute__((address_space(3))) unsigned int*)l, 16, 0, 0);
}

DEV f32x4 mfma16(s16x8 a, s16x8 b, f32x4 c) {
  return __builtin_amdgcn_mfma_f32_16x16x32_bf16(a, b, c, 0, 0, 0);
}
DEV f32x16 mfma32(s16x8 a, s16x8 b, f32x16 c) {
  return __builtin_amdgcn_mfma_f32_32x32x16_bf16(a, b, c, 0, 0, 0);
}

// ---------------------------------------------------------------------------
// Weight fp32 -> bf16 conversion
// ---------------------------------------------------------------------------
__global__ void k_cvt_w(const float* __restrict__ w0, const float* __restrict__ w1,
                        const float* __restrict__ w2, const float* __restrict__ w3,
                        u16* __restrict__ out) {
  int i = blockIdx.x * 256 + threadIdx.x;
  int which = i >> 18, off = i & 0x3ffff;
  const float* s = which == 0 ? w0 : which == 1 ? w1 : which == 2 ? w2 : w3;
  out[i] = bf16b(s[off]);
}

// ---------------------------------------------------------------------------
// GroupNorm: x[b,c,n] fp32 -> hT[b,n,c] bf16
// ---------------------------------------------------------------------------
__global__ __launch_bounds__(1024) void k_gn(const float* __restrict__ x,
                                             const float* __restrict__ gsc,
                                             const float* __restrict__ gbi,
                                             u16* __restrict__ hT) {
  const int b = blockIdx.x >> 5, g = blockIdx.x & 31;
  const int tid = threadIdx.x;
  const float* xs = x + (size_t)(b * 512 + g * 16) * 4096;

  float s = 0.f, s2 = 0.f;
  const float4* xv = (const float4*)xs;
  #pragma unroll
  for (int kq = 0; kq < 16; kq++) {
    float4 v = xv[tid + kq * 1024];
    s  += v.x + v.y + v.z + v.w;
    s2 += v.x * v.x + v.y * v.y + v.z * v.z + v.w * v.w;
  }
  #pragma unroll
  for (int m = 1; m < 64; m <<= 1) { s += __shfl_xor(s, m, 64); s2 += __shfl_xor(s2, m, 64); }
  __shared__ float rs[16], rs2[16];
  __shared__ float stat[2];
  int wid = tid >> 6;
  if ((tid & 63) == 0) { rs[wid] = s; rs2[wid] = s2; }
  __syncthreads();
  if (tid == 0) {
    float a = 0.f, a2 = 0.f;
    for (int i = 0; i < 16; i++) { a += rs[i]; a2 += rs2[i]; }
    float mean = a * (1.f / 65536.f);
    float var = a2 * (1.f / 65536.f) - mean * mean;
    stat[0] = mean;
    stat[1] = rsqrtf(var + 1e-6f);
  }
  __syncthreads();
  const float mean = stat[0], rstd = stat[1];
  const int cc = tid & 15;
  const float aa = rstd * gsc[g * 16 + cc];
  const float bb = gbi[g * 16 + cc] - mean * aa;

  __shared__ float tile[16][257];
  u16* ho = hT + (size_t)b * 4096 * 512 + g * 16;
  for (int n0 = 0; n0 < 4096; n0 += 256) {
    __syncthreads();
    #pragma unroll
    for (int rr = 0; rr < 4; rr++) {
      int r = rr * 4 + (tid >> 8);
      tile[r][tid & 255] = xs[(size_t)r * 4096 + n0 + (tid & 255)];
    }
    __syncthreads();
    #pragma unroll
    for (int kq = 0; kq < 4; kq++) {
      int nl = ((tid >> 4) << 2) + kq;
      float v = tile[cc][nl];
      ho[(size_t)(n0 + nl) * 512 + cc] = bf16b(v * aa + bb);
    }
  }
}

// ---------------------------------------------------------------------------
// NT GEMM core v2: double-buffered LDS, 1 barrier per K-step.
// C[M,N] = A[M,512] * B[N,512]^T (+bias, +optional resid)
// ---------------------------------------------------------------------------
template<bool BIAS_ROW, bool RESID>
DEV void gemm_nt_core(const u16* __restrict__ A, const u16* __restrict__ Bm,
                      const float* __restrict__ bias, const float* __restrict__ resid,
                      void* __restrict__ outp, int m0, int n0, int ldo) {
  __shared__ __align__(16) u16 As[2][128 * 64];
  __shared__ __align__(16) u16 Bs[2][128 * 64];
  const int tid = threadIdx.x;
  const int lane = tid & 63;
  const int w = tid >> 6;
  const int wr = w >> 1, wc = w & 1;
  f32x4 acc[4][4] = {};

  #define STAGE_G(kc, buf)                                                    \
    {                                                                         \
      int koffb = (kc) * 64;                                                  \
      _Pragma("unroll")                                                       \
      for (int q = 0; q < 4; q++) {                                           \
        int idx = q * 256 + tid;                                              \
        int row = idx >> 3, sl = idx & 7;                                     \
        int koff = koffb + ((sl ^ (row & 7)) << 3);                           \
        gload16(A  + (size_t)(m0 + row) * 512 + koff, As[buf] + (q * 256 + w * 64) * 8); \
        gload16(Bm + (size_t)(n0 + row) * 512 + koff, Bs[buf] + (q * 256 + w * 64) * 8); \
      }                                                                       \
    }

  STAGE_G(0, 0);
  __syncthreads();

  for (int kc = 0; kc < 8; kc++) {
    const int cur = kc & 1;
    if (kc < 7) STAGE_G(kc + 1, cur ^ 1);
    #pragma unroll
    for (int kk = 0; kk < 2; kk++) {
      s16x8 af[4], bfr[4];
      #pragma unroll
      for (int m = 0; m < 4; m++) {
        int row = wr * 64 + m * 16 + (lane & 15);
        int cq = kk * 4 + (lane >> 4);
        af[m] = *(const s16x8*)&As[cur][row * 64 + ((cq ^ (row & 7)) << 3)];
      }
      #pragma unroll
      for (int n = 0; n < 4; n++) {
        int row = wc * 64 + n * 16 + (lane & 15);
        int cq = kk * 4 + (lane >> 4);
        bfr[n] = *(const s16x8*)&Bs[cur][row * 64 + ((cq ^ (row & 7)) << 3)];
      }
      #pragma unroll
      for (int m = 0; m < 4; m++)
        #pragma unroll
        for (int n = 0; n < 4; n++)
          acc[m][n] = mfma16(af[m], bfr[n], acc[m][n]);
    }
    __syncthreads();
  }
  #undef STAGE_G

  float bcol[4];
  if (!BIAS_ROW) {
    #pragma unroll
    for (int n = 0; n < 4; n++) bcol[n] = bias[n0 + wc * 64 + n * 16 + (lane & 15)];
  }
  #pragma unroll
  for (int m = 0; m < 4; m++) {
    #pragma unroll
    for (int r = 0; r < 4; r++) {
      int row = m0 + wr * 64 + m * 16 + ((lane >> 4) << 2) + r;
      float badd = BIAS_ROW ? bias[row] : 0.f;
      #pragma unroll
      for (int n = 0; n < 4; n++) {
        int col = n0 + wc * 64 + n * 16 + (lane & 15);
        float v = acc[m][n][r] + (BIAS_ROW ? badd : bcol[n]);
        if (RESID) {
          size_t o = (size_t)row * ldo + col;
          ((float*)outp)[o] = v + resid[o];
        } else {
          ((u16*)outp)[(size_t)row * ldo + col] = bf16b(v);
        }
      }
    }
  }
}

__global__ __launch_bounds__(256) void k_gemm_qk(const u16* __restrict__ hT,
    const u16* __restrict__ wqb, const u16* __restrict__ wkb,
    const float* __restrict__ bq, const float* __restrict__ bk,
    u16* __restrict__ qT, u16* __restrict__ kT) {
  int z = blockIdx.z, b = z >> 1;
  const u16* A = hT + (size_t)b * 4096 * 512;
  const u16* W = (z & 1) ? wkb : wqb;
  const float* bb = (z & 1) ? bk : bq;
  u16* out = ((z & 1) ? kT : qT) + (size_t)b * 4096 * 512;
  gemm_nt_core<false, false>(A, W, bb, nullptr, out, blockIdx.x * 128, blockIdx.y * 128, 512);
}

__global__ __launch_bounds__(256) void k_gemm_v(const u16* __restrict__ wvb,
    const u16* __restrict__ hT, const float* __restrict__ bv, u16* __restrict__ vS) {
  int b = blockIdx.z;
  gemm_nt_core<true, false>(wvb, hT + (size_t)b * 4096 * 512, bv, nullptr,
                            vS + (size_t)b * 512 * 4096, blockIdx.x * 128, blockIdx.y * 128, 4096);
}

__global__ __launch_bounds__(256) void k_gemm_o(const u16* __restrict__ wob,
    const u16* __restrict__ oT, const float* __restrict__ bo,
    const float* __restrict__ x, float* __restrict__ y) {
  int b = blockIdx.z;
  gemm_nt_core<true, true>(wob, oT + (size_t)b * 4096 * 512, bo,
                           x + (size_t)b * 512 * 4096,
                           y + (size_t)b * 512 * 4096, blockIdx.x * 128, blockIdx.y * 128, 4096);
}

// ---------------------------------------------------------------------------
// Fused attention v3: ONE barrier per jt.
//  - K: LDS double-buffer (2x32KB), staged via gload_lds one jt ahead.
//  - V: registers, direct global loads (LLC-resident), issued one phase ahead.
//  - P: LDS double-buffer (2x4KB).
//  Order per jt: PV(jt-1) | issue vf(jt) | issue Kstage(jt+1) | S(jt)+Pwrite | sync
//  S-phase uses 4 independent accumulation chains (breaks MFMA latency chain).
// ---------------------------------------------------------------------------
__global__ __launch_bounds__(512) void k_attn(const u16* __restrict__ qT,
                                              const u16* __restrict__ kT,
                                              const u16* __restrict__ vS,
                                              u16* __restrict__ oT) {
  const int it = blockIdx.x, b = blockIdx.y;
  const int tid = threadIdx.x, lane = tid & 63, w = tid >> 6;
  const int rg = w >> 1, cg = w & 1;       // S: 4x2 wave grid (16 rows x 16 cols each)
  const int rg2 = w >> 2, cg2 = w & 3;     // PV: 2x4 wave grid (32 rows x 128 cols each)

  const u16* qp = qT + (size_t)b * 4096 * 512;
  const u16* kp = kT + (size_t)b * 4096 * 512;
  const u16* vp = vS + (size_t)b * 512 * 4096;

  __shared__ __align__(16) u16 Ks[2][32 * 512];   // 64KB, slot q^(j&7)
  __shared__ __align__(16) u16 Ps[2][64 * 32];    // 8KB,  slot q^(i&3)
  __shared__ float l_lds[2][64];

  // Q fragments: wave's 16 rows x K=512 (16x16x32 A layout)
  s16x8 qf[16];
  {
    const u16* qrow = qp + (size_t)(it * 64 + rg * 16 + (lane & 15)) * 512 + ((lane >> 4) << 3);
    #pragma unroll
    for (int t = 0; t < 16; t++) qf[t] = *(const s16x8*)(qrow + t * 32);
  }
  f32x16 oacc[4] = {};
  float lpart[4] = {0.f, 0.f, 0.f, 0.f};
  s16x8 vf[2][4];

  const int wbase = w * 64 * 8;
  const int sb = lane >> 5;
  const int jS = cg * 16 + (lane & 15);    // S-phase K row (0..31)
  const int irow = rg2 * 32 + (lane & 31); // PV P row
  const u16* vbase = vp + (size_t)(cg2 * 128 + (lane & 31)) * 4096 + sb * 8;

  // prologue: stage K(0)
  #pragma unroll
  for (int q = 0; q < 4; q++) {
    int d = q * 512 + tid, j = d >> 6, p = d & 63;
    gload16(kp + (size_t)j * 512 + ((p ^ (j & 7)) << 3), Ks[0] + q * 4096 + wbase);
  }
  __syncthreads();

  const float se = 0.044194173824159216f;  // 1/sqrt(512)

  for (int jt = 0; jt < 128; jt++) {
    const int cur = jt & 1;

    // ---- A: PV(jt-1) from Ps[cur^1] and vf
    if (jt > 0) {
      const u16* pr = Ps[cur ^ 1] + irow * 32;
      #pragma unroll
      for (int ks = 0; ks < 2; ks++) {
        int q = ks * 2 + sb;
        s16x8 pf = *(const s16x8*)(pr + ((q ^ (irow & 3)) << 3));
        #pragma unroll
        for (int n = 0; n < 4; n++) oacc[n] = mfma32(pf, vf[ks][n], oacc[n]);
      }
    }
    // ---- B: issue vf(jt) direct-global loads (consumed at A of jt+1)
    {
      const u16* vj = vbase + jt * 32;
      #pragma unroll
      for (int ks = 0; ks < 2; ks++)
        #pragma unroll
        for (int n = 0; n < 4; n++)
          vf[ks][n] = *(const s16x8*)(vj + (size_t)n * 32 * 4096 + ks * 16);
    }
    // ---- C: issue K-stage(jt+1) into Ks[cur^1]
    if (jt < 127) {
      const u16* kn = kp + (size_t)(jt + 1) * 32 * 512;
      #pragma unroll
      for (int q = 0; q < 4; q++) {
        int d = q * 512 + tid, j = d >> 6, p = d & 63;
        gload16(kn + (size_t)j * 512 + ((p ^ (j & 7)) << 3), Ks[cur ^ 1] + q * 4096 + wbase);
      }
    }
    // ---- D: S-phase on Ks[cur], 4 accumulation chains, P-write to Ps[cur]
    {
      f32x4 sc[4] = {{}, {}, {}, {}};
      const u16* kb = Ks[cur] + jS * 512;
      const int xm = (jS & 7) << 3;
      #pragma unroll
      for (int t = 0; t < 16; t++) {
        int off = ((t * 4 + (lane >> 4)) << 3) ^ xm;
        sc[t & 3] = mfma16(qf[t], *(const s16x8*)(kb + off), sc[t & 3]);
      }
      f32x4 sm = (sc[0] + sc[1]) + (sc[2] + sc[3]);
      #pragma unroll
      for (int r = 0; r < 4; r++) {
        float pv = __expf(sm[r] * se);
        lpart[r] += pv;
        int grow = rg * 16 + ((lane >> 4) << 2) + r;
        Ps[cur][grow * 32 + (((jS >> 3) ^ (grow & 3)) << 3) + (jS & 7)] = bf16b(pv);
      }
    }
    __syncthreads();   // single barrier: drains K-stage + vf + P-writes
  }

  // ---- final PV(127): Ps[1], vf holds tile 127
  {
    const u16* pr = Ps[1] + irow * 32;
    #pragma unroll
    for (int ks = 0; ks < 2; ks++) {
      int q = ks * 2 + sb;
      s16x8 pf = *(const s16x8*)(pr + ((q ^ (irow & 3)) << 3));
      #pragma unroll
      for (int n = 0; n < 4; n++) oacc[n] = mfma32(pf, vf[ks][n], oacc[n]);
    }
  }

  // ---- epilogue: row-sum reduce l, divide, write oT
  #pragma unroll
  for (int r = 0; r < 4; r++) {
    float lv = lpart[r];
    lv += __shfl_xor(lv, 1, 64);
    lv += __shfl_xor(lv, 2, 64);
    lv += __shfl_xor(lv, 4, 64);
    lv += __shfl_xor(lv, 8, 64);
    if ((lane & 15) == 0) l_lds[cg][rg * 16 + ((lane >> 4) << 2) + r] = lv;
  }
  __syncthreads();

  float linv[16];
  #pragma unroll
  for (int e = 0; e < 16; e++) {
    int i = rg2 * 32 + (e & 3) + 8 * (e >> 2) + 4 * sb;
    linv[e] = 1.0f / (l_lds[0][i] + l_lds[1][i]);
  }
  u16* op = oT + ((size_t)b * 4096 + it * 64) * 512;
  #pragma unroll
  for (int n = 0; n < 4; n++) {
    int col = cg2 * 128 + n * 32 + (lane & 31);
    #pragma unroll
    for (int e = 0; e < 16; e++) {
      int i = rg2 * 32 + (e & 3) + 8 * (e >> 2) + 4 * sb;
      op[(size_t)i * 512 + col] = bf16b(oacc[n][e] * linv[e]);
    }
  }
}

// ---------------------------------------------------------------------------
extern "C" void kernel_launch(void* const* d_in, const int* in_sizes, int n_in,
                              void* d_out, int out_size, void* d_ws, size_t ws_size,
                              hipStream_t stream) {
  const float* x   = (const float*)d_in[0];
  const float* gsc = (const float*)d_in[1];
  const float* gbi = (const float*)d_in[2];
  const float* wq  = (const float*)d_in[3];
  const float* bq  = (const float*)d_in[4];
  const float* wk  = (const float*)d_in[5];
  const float* bk  = (const float*)d_in[6];
  const float* wv  = (const float*)d_in[7];
  const float* bv  = (const float*)d_in[8];
  const float* wo  = (const float*)d_in[9];
  const float* bo  = (const float*)d_in[10];
  float* out = (float*)d_out;
  char* ws = (char*)d_ws;

  u16* hT = (u16*)ws;                                // also reused as oT
  u16* vS = (u16*)(ws + ((size_t)32 << 20));
  u16* wB = (u16*)(ws + ((size_t)64 << 20));
  u16* wqb = wB;
  u16* wkb = wB + 262144;
  u16* wvb = wB + 2 * 262144;
  u16* wob = wB + 3 * 262144;
  u16* qT = (u16*)d_out;
  u16* kT = qT + (size_t)8 * 4096 * 512;

  k_cvt_w<<<4096, 256, 0, stream>>>(wq, wk, wv, wo, wB);
  k_gn<<<256, 1024, 0, stream>>>(x, gsc, gbi, hT);
  k_gemm_qk<<<dim3(32, 4, 16), 256, 0, stream>>>(hT, wqb, wkb, bq, bk, qT, kT);
  k_gemm_v<<<dim3(4, 32, 8), 256, 0, stream>>>(wvb, hT, bv, vS);
  k_attn<<<dim3(64, 8), 512, 0, stream>>>(qT, kT, vS, hT /* = oT */);
  k_gemm_o<<<dim3(4, 32, 8), 256, 0, stream>>>(wob, hT, bo, x, out);
}

// Round 4
// 712.707 us; speedup vs baseline: 1.4875x; 1.4875x over previous
//
#include <hip/hip_runtime.h>

using u16 = unsigned short;
using s16x8 = __attribute__((ext_vector_type(8))) short;
using f32x4 = __attribute__((ext_vector_type(4))) float;
using f32x16 = __attribute__((ext_vector_type(16))) float;

#define DEV static __device__ __forceinline__

DEV u16 bf16b(float f) {
  unsigned u = __builtin_bit_cast(unsigned, f);
  return (u16)((u + 0x7fffu + ((u >> 16) & 1u)) >> 16);
}

DEV void gload16(const void* g, void* l) {
  __builtin_amdgcn_global_load_lds((const __attribute__((address_space(1))) unsigned int*)g,
                                   (__attribute__((address_space(3))) unsigned int*)l, 16, 0, 0);
}

DEV f32x4 mfma16(s16x8 a, s16x8 b, f32x4 c) {
  return __builtin_amdgcn_mfma_f32_16x16x32_bf16(a, b, c, 0, 0, 0);
}
DEV f32x16 mfma32(s16x8 a, s16x8 b, f32x16 c) {
  return __builtin_amdgcn_mfma_f32_32x32x16_bf16(a, b, c, 0, 0, 0);
}

// ---------------------------------------------------------------------------
// Weight fp32 -> bf16 conversion
// ---------------------------------------------------------------------------
__global__ void k_cvt_w(const float* __restrict__ w0, const float* __restrict__ w1,
                        const float* __restrict__ w2, const float* __restrict__ w3,
                        u16* __restrict__ out) {
  int i = blockIdx.x * 256 + threadIdx.x;
  int which = i >> 18, off = i & 0x3ffff;
  const float* s = which == 0 ? w0 : which == 1 ? w1 : which == 2 ? w2 : w3;
  out[i] = bf16b(s[off]);
}

// ---------------------------------------------------------------------------
// GroupNorm: x[b,c,n] fp32 -> hT[b,n,c] bf16
// ---------------------------------------------------------------------------
__global__ __launch_bounds__(1024) void k_gn(const float* __restrict__ x,
                                             const float* __restrict__ gsc,
                                             const float* __restrict__ gbi,
                                             u16* __restrict__ hT) {
  const int b = blockIdx.x >> 5, g = blockIdx.x & 31;
  const int tid = threadIdx.x;
  const float* xs = x + (size_t)(b * 512 + g * 16) * 4096;

  float s = 0.f, s2 = 0.f;
  const float4* xv = (const float4*)xs;
  #pragma unroll
  for (int kq = 0; kq < 16; kq++) {
    float4 v = xv[tid + kq * 1024];
    s  += v.x + v.y + v.z + v.w;
    s2 += v.x * v.x + v.y * v.y + v.z * v.z + v.w * v.w;
  }
  #pragma unroll
  for (int m = 1; m < 64; m <<= 1) { s += __shfl_xor(s, m, 64); s2 += __shfl_xor(s2, m, 64); }
  __shared__ float rs[16], rs2[16];
  __shared__ float stat[2];
  int wid = tid >> 6;
  if ((tid & 63) == 0) { rs[wid] = s; rs2[wid] = s2; }
  __syncthreads();
  if (tid == 0) {
    float a = 0.f, a2 = 0.f;
    for (int i = 0; i < 16; i++) { a += rs[i]; a2 += rs2[i]; }
    float mean = a * (1.f / 65536.f);
    float var = a2 * (1.f / 65536.f) - mean * mean;
    stat[0] = mean;
    stat[1] = rsqrtf(var + 1e-6f);
  }
  __syncthreads();
  const float mean = stat[0], rstd = stat[1];
  const int cc = tid & 15;
  const float aa = rstd * gsc[g * 16 + cc];
  const float bb = gbi[g * 16 + cc] - mean * aa;

  __shared__ float tile[16][257];
  u16* ho = hT + (size_t)b * 4096 * 512 + g * 16;
  for (int n0 = 0; n0 < 4096; n0 += 256) {
    __syncthreads();
    #pragma unroll
    for (int rr = 0; rr < 4; rr++) {
      int r = rr * 4 + (tid >> 8);
      tile[r][tid & 255] = xs[(size_t)r * 4096 + n0 + (tid & 255)];
    }
    __syncthreads();
    #pragma unroll
    for (int kq = 0; kq < 4; kq++) {
      int nl = ((tid >> 4) << 2) + kq;
      float v = tile[cc][nl];
      ho[(size_t)(n0 + nl) * 512 + cc] = bf16b(v * aa + bb);
    }
  }
}

// ---------------------------------------------------------------------------
// NT GEMM core: double-buffered LDS, 1 barrier per K-step.
// ---------------------------------------------------------------------------
template<bool BIAS_ROW, bool RESID>
DEV void gemm_nt_core(const u16* __restrict__ A, const u16* __restrict__ Bm,
                      const float* __restrict__ bias, const float* __restrict__ resid,
                      void* __restrict__ outp, int m0, int n0, int ldo) {
  __shared__ __align__(16) u16 As[2][128 * 64];
  __shared__ __align__(16) u16 Bs[2][128 * 64];
  const int tid = threadIdx.x;
  const int lane = tid & 63;
  const int w = tid >> 6;
  const int wr = w >> 1, wc = w & 1;
  f32x4 acc[4][4] = {};

  #define STAGE_G(kc, buf)                                                    \
    {                                                                         \
      int koffb = (kc) * 64;                                                  \
      _Pragma("unroll")                                                       \
      for (int q = 0; q < 4; q++) {                                           \
        int idx = q * 256 + tid;                                              \
        int row = idx >> 3, sl = idx & 7;                                     \
        int koff = koffb + ((sl ^ (row & 7)) << 3);                           \
        gload16(A  + (size_t)(m0 + row) * 512 + koff, As[buf] + (q * 256 + w * 64) * 8); \
        gload16(Bm + (size_t)(n0 + row) * 512 + koff, Bs[buf] + (q * 256 + w * 64) * 8); \
      }                                                                       \
    }

  STAGE_G(0, 0);
  __syncthreads();

  for (int kc = 0; kc < 8; kc++) {
    const int cur = kc & 1;
    if (kc < 7) STAGE_G(kc + 1, cur ^ 1);
    #pragma unroll
    for (int kk = 0; kk < 2; kk++) {
      s16x8 af[4], bfr[4];
      #pragma unroll
      for (int m = 0; m < 4; m++) {
        int row = wr * 64 + m * 16 + (lane & 15);
        int cq = kk * 4 + (lane >> 4);
        af[m] = *(const s16x8*)&As[cur][row * 64 + ((cq ^ (row & 7)) << 3)];
      }
      #pragma unroll
      for (int n = 0; n < 4; n++) {
        int row = wc * 64 + n * 16 + (lane & 15);
        int cq = kk * 4 + (lane >> 4);
        bfr[n] = *(const s16x8*)&Bs[cur][row * 64 + ((cq ^ (row & 7)) << 3)];
      }
      #pragma unroll
      for (int m = 0; m < 4; m++)
        #pragma unroll
        for (int n = 0; n < 4; n++)
          acc[m][n] = mfma16(af[m], bfr[n], acc[m][n]);
    }
    __syncthreads();
  }
  #undef STAGE_G

  float bcol[4];
  if (!BIAS_ROW) {
    #pragma unroll
    for (int n = 0; n < 4; n++) bcol[n] = bias[n0 + wc * 64 + n * 16 + (lane & 15)];
  }
  #pragma unroll
  for (int m = 0; m < 4; m++) {
    #pragma unroll
    for (int r = 0; r < 4; r++) {
      int row = m0 + wr * 64 + m * 16 + ((lane >> 4) << 2) + r;
      float badd = BIAS_ROW ? bias[row] : 0.f;
      #pragma unroll
      for (int n = 0; n < 4; n++) {
        int col = n0 + wc * 64 + n * 16 + (lane & 15);
        float v = acc[m][n][r] + (BIAS_ROW ? badd : bcol[n]);
        if (RESID) {
          size_t o = (size_t)row * ldo + col;
          ((float*)outp)[o] = v + resid[o];
        } else {
          ((u16*)outp)[(size_t)row * ldo + col] = bf16b(v);
        }
      }
    }
  }
}

__global__ __launch_bounds__(256) void k_gemm_qk(const u16* __restrict__ hT,
    const u16* __restrict__ wqb, const u16* __restrict__ wkb,
    const float* __restrict__ bq, const float* __restrict__ bk,
    u16* __restrict__ qT, u16* __restrict__ kT) {
  int z = blockIdx.z, b = z >> 1;
  const u16* A = hT + (size_t)b * 4096 * 512;
  const u16* W = (z & 1) ? wkb : wqb;
  const float* bb = (z & 1) ? bk : bq;
  u16* out = ((z & 1) ? kT : qT) + (size_t)b * 4096 * 512;
  gemm_nt_core<false, false>(A, W, bb, nullptr, out, blockIdx.x * 128, blockIdx.y * 128, 512);
}

__global__ __launch_bounds__(256) void k_gemm_v(const u16* __restrict__ wvb,
    const u16* __restrict__ hT, const float* __restrict__ bv, u16* __restrict__ vS) {
  int b = blockIdx.z;
  gemm_nt_core<true, false>(wvb, hT + (size_t)b * 4096 * 512, bv, nullptr,
                            vS + (size_t)b * 512 * 4096, blockIdx.x * 128, blockIdx.y * 128, 4096);
}

__global__ __launch_bounds__(256) void k_gemm_o(const u16* __restrict__ wob,
    const u16* __restrict__ oT, const float* __restrict__ bo,
    const float* __restrict__ x, float* __restrict__ y) {
  int b = blockIdx.z;
  gemm_nt_core<true, true>(wob, oT + (size_t)b * 4096 * 512, bo,
                           x + (size_t)b * 512 * 4096,
                           y + (size_t)b * 512 * 4096, blockIdx.x * 128, blockIdx.y * 128, 4096);
}

// ---------------------------------------------------------------------------
// Fused attention v4: counted-vmcnt raw barriers (T3/T4), two phases per jt.
//  Phase A(jt): issue V(jt+1); S(jt) = Q K^T (Q regs, K LDS); exp; P->LDS.
//               [vmcnt(8) lgkmcnt(0)] barrier
//  Phase B(jt): issue K(jt+2); PV(jt) via 32x32x16 (P LDS, V LDS).
//               [vmcnt(8)] barrier
//  Stages in flight across barriers; vmcnt never drained to 0 in the loop.
//  Tail uses wrapped bogus stages to keep per-wave vmcnt counts uniform.
// ---------------------------------------------------------------------------
__global__ __launch_bounds__(512) void k_attn(const u16* __restrict__ qT,
                                              const u16* __restrict__ kT,
                                              const u16* __restrict__ vS,
                                              u16* __restrict__ oT) {
  const int it = blockIdx.x, b = blockIdx.y;
  const int tid = threadIdx.x, lane = tid & 63, w = tid >> 6;
  const int rg = w >> 1, cg = w & 1;       // S: 4x2 wave grid
  const int rg2 = w >> 2, cg2 = w & 3;     // PV: 2x4 wave grid

  const u16* qp = qT + (size_t)b * 4096 * 512;
  const u16* kp = kT + (size_t)b * 4096 * 512;
  const u16* vp = vS + (size_t)b * 512 * 4096;

  __shared__ __align__(16) u16 Ks[2][32 * 512];   // 64KB, slot q^(j&7)
  __shared__ __align__(16) u16 Vs[2][512 * 32];   // 64KB, slot s^((c>>1)&3)
  __shared__ __align__(16) u16 Ps[2][64 * 32];    // 8KB,  slot s^((i>>2)&3)
  __shared__ float l_lds[2][64];

  // Q fragments
  s16x8 qf[16];
  {
    const u16* qrow = qp + (size_t)(it * 64 + rg * 16 + (lane & 15)) * 512 + ((lane >> 4) << 3);
    #pragma unroll
    for (int t = 0; t < 16; t++) qf[t] = *(const s16x8*)(qrow + t * 32);
  }
  f32x16 oacc[4] = {};
  float lpart[4] = {0.f, 0.f, 0.f, 0.f};

  const int wbase = w * 64 * 8;
  const int sb = lane >> 5;
  const int jS = cg * 16 + (lane & 15);
  const int irow = rg2 * 32 + (lane & 31);
  const int ppermbase = (irow >> 2) & 3;

  #define KSTAGE(t, buf)                                                       \
    { const u16* kn = kp + (size_t)((t) & 127) * 32 * 512;                     \
      _Pragma("unroll")                                                        \
      for (int q = 0; q < 4; q++) {                                            \
        int d = q * 512 + tid, j = d >> 6, p = d & 63;                         \
        gload16(kn + (size_t)j * 512 + ((p ^ (j & 7)) << 3), Ks[buf] + q * 4096 + wbase); } }
  #define VSTAGE(t, buf)                                                       \
    { const u16* vn = vp + (size_t)((t) & 127) * 32;                           \
      _Pragma("unroll")                                                        \
      for (int q = 0; q < 4; q++) {                                            \
        int d = q * 512 + tid, c = d >> 2, p = d & 3;                          \
        gload16(vn + (size_t)c * 4096 + ((p ^ ((c >> 1) & 3)) << 3), Vs[buf] + q * 4096 + wbase); } }

  // prologue: K(0), V(0), K(1) in flight; wait for K(0),V(0) only
  KSTAGE(0, 0);
  VSTAGE(0, 0);
  KSTAGE(1, 1);
  __builtin_amdgcn_sched_barrier(0);
  asm volatile("s_waitcnt vmcnt(8)" ::: "memory");
  __builtin_amdgcn_s_barrier();
  __builtin_amdgcn_sched_barrier(0);

  const float se = 0.044194173824159216f;  // 1/sqrt(512)

  for (int jt = 0; jt < 128; jt++) {
    const int cur = jt & 1;

    // ---- phase A: issue V(jt+1); S(jt); P write
    VSTAGE(jt + 1, cur ^ 1);
    {
      f32x4 sc[4] = {{}, {}, {}, {}};
      const u16* kb = Ks[cur] + jS * 512;
      const int xm = (jS & 7) << 3;
      __builtin_amdgcn_s_setprio(1);
      #pragma unroll
      for (int t = 0; t < 16; t++) {
        int off = ((t * 4 + (lane >> 4)) << 3) ^ xm;
        sc[t & 3] = mfma16(qf[t], *(const s16x8*)(kb + off), sc[t & 3]);
      }
      __builtin_amdgcn_s_setprio(0);
      f32x4 sm = (sc[0] + sc[1]) + (sc[2] + sc[3]);
      #pragma unroll
      for (int r = 0; r < 4; r++) {
        float pv = __expf(sm[r] * se);
        lpart[r] += pv;
        int grow = rg * 16 + ((lane >> 4) << 2) + r;
        // slot = (j>>3) ^ ((i>>2)&3); within instruction r this varies with q
        Ps[cur][grow * 32 + (((jS >> 3) ^ ((grow >> 2) & 3)) << 3) + (jS & 7)] = bf16b(pv);
      }
    }
    __builtin_amdgcn_sched_barrier(0);
    asm volatile("s_waitcnt vmcnt(8) lgkmcnt(0)" ::: "memory");
    __builtin_amdgcn_s_barrier();
    __builtin_amdgcn_sched_barrier(0);

    // ---- phase B: issue K(jt+2); PV(jt)
    KSTAGE(jt + 2, cur);
    {
      const u16* pr = Ps[cur] + irow * 32;
      __builtin_amdgcn_s_setprio(1);
      #pragma unroll
      for (int ks = 0; ks < 2; ks++) {
        int q8 = ks * 2 + sb;
        s16x8 pf = *(const s16x8*)(pr + ((q8 ^ ppermbase) << 3));
        #pragma unroll
        for (int n = 0; n < 4; n++) {
          int c = cg2 * 128 + n * 32 + (lane & 31);
          int vpp = q8 ^ ((c >> 1) & 3);
          s16x8 vf = *(const s16x8*)(Vs[cur] + c * 32 + (vpp & 3) * 8);
          oacc[n] = mfma32(pf, vf, oacc[n]);
        }
      }
      __builtin_amdgcn_s_setprio(0);
    }
    __builtin_amdgcn_sched_barrier(0);
    asm volatile("s_waitcnt vmcnt(8)" ::: "memory");
    __builtin_amdgcn_s_barrier();
    __builtin_amdgcn_sched_barrier(0);
  }
  #undef KSTAGE
  #undef VSTAGE

  __syncthreads();   // full drain (retires bogus tail stages)

  // ---- epilogue: row-sum reduce l, divide, write oT
  #pragma unroll
  for (int r = 0; r < 4; r++) {
    float lv = lpart[r];
    lv += __shfl_xor(lv, 1, 64);
    lv += __shfl_xor(lv, 2, 64);
    lv += __shfl_xor(lv, 4, 64);
    lv += __shfl_xor(lv, 8, 64);
    if ((lane & 15) == 0) l_lds[cg][rg * 16 + ((lane >> 4) << 2) + r] = lv;
  }
  __syncthreads();

  float linv[16];
  #pragma unroll
  for (int e = 0; e < 16; e++) {
    int i = rg2 * 32 + (e & 3) + 8 * (e >> 2) + 4 * sb;
    linv[e] = 1.0f / (l_lds[0][i] + l_lds[1][i]);
  }
  u16* op = oT + ((size_t)b * 4096 + it * 64) * 512;
  #pragma unroll
  for (int n = 0; n < 4; n++) {
    int col = cg2 * 128 + n * 32 + (lane & 31);
    #pragma unroll
    for (int e = 0; e < 16; e++) {
      int i = rg2 * 32 + (e & 3) + 8 * (e >> 2) + 4 * sb;
      op[(size_t)i * 512 + col] = bf16b(oacc[n][e] * linv[e]);
    }
  }
}

// ---------------------------------------------------------------------------
extern "C" void kernel_launch(void* const* d_in, const int* in_sizes, int n_in,
                              void* d_out, int out_size, void* d_ws, size_t ws_size,
                              hipStream_t stream) {
  const float* x   = (const float*)d_in[0];
  const float* gsc = (const float*)d_in[1];
  const float* gbi = (const float*)d_in[2];
  const float* wq  = (const float*)d_in[3];
  const float* bq  = (const float*)d_in[4];
  const float* wk  = (const float*)d_in[5];
  const float* bk  = (const float*)d_in[6];
  const float* wv  = (const float*)d_in[7];
  const float* bv  = (const float*)d_in[8];
  const float* wo  = (const float*)d_in[9];
  const float* bo  = (const float*)d_in[10];
  float* out = (float*)d_out;
  char* ws = (char*)d_ws;

  u16* hT = (u16*)ws;                                // also reused as oT
  u16* vS = (u16*)(ws + ((size_t)32 << 20));
  u16* wB = (u16*)(ws + ((size_t)64 << 20));
  u16* wqb = wB;
  u16* wkb = wB + 262144;
  u16* wvb = wB + 2 * 262144;
  u16* wob = wB + 3 * 262144;
  u16* qT = (u16*)d_out;
  u16* kT = qT + (size_t)8 * 4096 * 512;

  k_cvt_w<<<4096, 256, 0, stream>>>(wq, wk, wv, wo, wB);
  k_gn<<<256, 1024, 0, stream>>>(x, gsc, gbi, hT);
  k_gemm_qk<<<dim3(32, 4, 16), 256, 0, stream>>>(hT, wqb, wkb, bq, bk, qT, kT);
  k_gemm_v<<<dim3(4, 32, 8), 256, 0, stream>>>(wvb, hT, bv, vS);
  k_attn<<<dim3(64, 8), 512, 0, stream>>>(qT, kT, vS, hT /* = oT */);
  k_gemm_o<<<dim3(4, 32, 8), 256, 0, stream>>>(wob, hT, bo, x, out);
}